// Round 8
// baseline (546.959 us; speedup 1.0000x reference)
//
#include <hip/hip_runtime.h>
#include <hip/hip_fp16.h>

#define DIM 64
#define K_PASSES 8
#define EPT 8        // phase-1 elements/thread (EPT=16 halved occupancy: 185->306us)
#define BUCKET_CAP 16
#define OVF_CAP 65536

typedef int          vint4   __attribute__((ext_vector_type(4)));
typedef float        vfloat4 __attribute__((ext_vector_type(4)));
typedef unsigned int vuint4  __attribute__((ext_vector_type(4)));

static __device__ __forceinline__ float2 h2f2(unsigned u) {
    __half2 h = __builtin_bit_cast(__half2, u);
    return __half22float2(h);
}

// ---------- Phase 1: esum[g] = (half)(hw[widx[0][g]] + hw[widx[1][g]]) ----------
__global__ void emb_sum_kernel(const int* __restrict__ widx,
                               const float* __restrict__ hw,
                               __half* __restrict__ esum,
                               long long total, int hashed_size) {
    long long base = ((long long)blockIdx.x * blockDim.x + threadIdx.x) * EPT;
    if (base >= total) return;
    if (base + EPT <= total) {
        const vint4* w0 = (const vint4*)(widx + base);
        const vint4* w1 = (const vint4*)(widx + base + total);
        vint4 a0 = __builtin_nontemporal_load(w0);
        vint4 a1 = __builtin_nontemporal_load(w0 + 1);
        vint4 b0 = __builtin_nontemporal_load(w1);
        vint4 b1 = __builtin_nontemporal_load(w1 + 1);
        int idx[16] = {a0.x, a0.y, a0.z, a0.w, a1.x, a1.y, a1.z, a1.w,
                       b0.x, b0.y, b0.z, b0.w, b1.x, b1.y, b1.z, b1.w};
        float r[16];
#pragma unroll
        for (int i = 0; i < 16; ++i) r[i] = 0.0f;
        int slice = (hashed_size + K_PASSES - 1) / K_PASSES;
        int lo = 0;
        for (int k = 0; k < K_PASSES; ++k, lo += slice) {
#pragma unroll
            for (int i = 0; i < 16; ++i) {
                if ((unsigned)(idx[i] - lo) < (unsigned)slice)
                    r[i] += hw[idx[i]];
            }
        }
        unsigned u[4];
#pragma unroll
        for (int p = 0; p < 4; ++p) {
            float s0 = r[2 * p] + r[8 + 2 * p];
            float s1 = r[2 * p + 1] + r[8 + 2 * p + 1];
            __half2 h = __halves2half2(__float2half_rn(s0), __float2half_rn(s1));
            u[p] = __builtin_bit_cast(unsigned, h);
        }
        vuint4 o0 = {u[0], u[1], u[2], u[3]};
        __builtin_nontemporal_store(o0, (vuint4*)(esum + base));
    } else {
        for (long long g = base; g < total; ++g)
            esum[g] = __float2half_rn(hw[widx[g]] + hw[widx[g + total]]);
    }
}

static __device__ __forceinline__ int bag_of(int t, const int* __restrict__ offsets,
                                             int num_bags, int total_tokens) {
    int avg = total_tokens / num_bags;
    int b = t / avg;
    if (b >= num_bags) b = num_bags - 1;
    while (t < offsets[b]) --b;
    while (b + 1 < num_bags && t >= offsets[b + 1]) ++b;
    return b;
}

// ---------- Phase 1.5: bin tokens by embedding id ----------
__global__ void bin_kernel(const int* __restrict__ x,
                           const int* __restrict__ offsets,
                           int* __restrict__ counts,
                           int* __restrict__ buckets,
                           int* __restrict__ ovf_cnt,
                           int* __restrict__ ovf,
                           int total_tokens, int num_bags) {
    int t = blockIdx.x * blockDim.x + threadIdx.x;
    if (t >= total_tokens) return;
    int e = x[t];
    int b = bag_of(t, offsets, num_bags, total_tokens);
    int slot = atomicAdd(&counts[e], 1);
    if (slot < BUCKET_CAP) {
        buckets[(size_t)e * BUCKET_CAP + slot] = b;
    } else {
        int o = atomicAdd(ovf_cnt, 1);
        if (o < OVF_CAP) ovf[o] = t;
    }
}

// ---------- Phase 2: one wave per embedding; scatter row into bags ----------
__global__ void scatter_kernel(const __half* __restrict__ esum,
                               const int* __restrict__ counts,
                               const int* __restrict__ buckets,
                               float* __restrict__ out,
                               int num_emb) {
    int wave = (int)((blockIdx.x * blockDim.x + threadIdx.x) >> 6);
    int lane = threadIdx.x & 63;
    if (wave >= num_emb) return;
    int c = counts[wave];
    if (c == 0) return;
    if (c > BUCKET_CAP) c = BUCKET_CAP;
    float v = __half2float(esum[(size_t)wave * DIM + lane]);
    const int* bk = buckets + (size_t)wave * BUCKET_CAP;
    for (int s = 0; s < c; ++s) {
        int b = bk[s];
        atomicAdd(out + (size_t)b * DIM + lane, v);
    }
}

// ---------- Overflow tokens (expected ~0): direct scatter ----------
__global__ void overflow_kernel(const int* __restrict__ x,
                                const int* __restrict__ offsets,
                                const __half* __restrict__ esum,
                                float* __restrict__ out,
                                const int* __restrict__ ovf_cnt,
                                const int* __restrict__ ovf,
                                int total_tokens, int num_bags) {
    int cnt = *ovf_cnt;
    if (cnt > OVF_CAP) cnt = OVF_CAP;
    int lane = threadIdx.x & 63;
    int wave = (int)((blockIdx.x * blockDim.x + threadIdx.x) >> 6);
    int nwaves = (gridDim.x * blockDim.x) >> 6;
    for (int i = wave; i < cnt; i += nwaves) {
        int t = ovf[i];
        int e = x[t];
        int b = bag_of(t, offsets, num_bags, total_tokens);
        float v = __half2float(esum[(size_t)e * DIM + lane]);
        atomicAdd(out + (size_t)b * DIM + lane, v);
    }
}

// ---------- Fallback phase 2 (gather) if ws too small for binning ----------
__global__ void __launch_bounds__(256, 8)
bag_sum_kernel(const int* __restrict__ x,
               const int* __restrict__ offsets,
               const __half* __restrict__ esum,
               float* __restrict__ out,
               int num_bags, int total_tokens) {
    int wave = (int)((blockIdx.x * blockDim.x + threadIdx.x) >> 6);
    int lane = threadIdx.x & 63;
    if (wave >= num_bags) return;
    int group = lane >> 3, l8 = lane & 7;
    int start = offsets[wave];
    int end = (wave + 1 < num_bags) ? offsets[wave + 1] : total_tokens;
    float2 acc0 = {0.f,0.f}, acc1 = {0.f,0.f}, acc2 = {0.f,0.f}, acc3 = {0.f,0.f};
    for (int base = start; base < end; base += 64) {
        int nn = end - base; if (nn > 64) nn = 64;
        int xv = (lane < nn) ? x[base + lane] : 0;
        int i = 0;
        for (; i + 8 <= nn; i += 8) {
            int eo = __shfl(xv, i + group, 64);
            vuint4 v = ((const vuint4*)(esum + (size_t)eo * DIM))[l8];
            float2 f0 = h2f2(v.x), f1 = h2f2(v.y), f2 = h2f2(v.z), f3 = h2f2(v.w);
            acc0.x += f0.x; acc0.y += f0.y; acc1.x += f1.x; acc1.y += f1.y;
            acc2.x += f2.x; acc2.y += f2.y; acc3.x += f3.x; acc3.y += f3.y;
        }
        if (i < nn) {
            int r = nn - i;
            int src = i + group; if (src > nn - 1) src = nn - 1;
            int eo = __shfl(xv, src, 64);
            vuint4 v = ((const vuint4*)(esum + (size_t)eo * DIM))[l8];
            if (group < r) {
                float2 f0 = h2f2(v.x), f1 = h2f2(v.y), f2 = h2f2(v.z), f3 = h2f2(v.w);
                acc0.x += f0.x; acc0.y += f0.y; acc1.x += f1.x; acc1.y += f1.y;
                acc2.x += f2.x; acc2.y += f2.y; acc3.x += f3.x; acc3.y += f3.y;
            }
        }
    }
#pragma unroll
    for (int m = 8; m <= 32; m <<= 1) {
        acc0.x += __shfl_xor(acc0.x, m, 64); acc0.y += __shfl_xor(acc0.y, m, 64);
        acc1.x += __shfl_xor(acc1.x, m, 64); acc1.y += __shfl_xor(acc1.y, m, 64);
        acc2.x += __shfl_xor(acc2.x, m, 64); acc2.y += __shfl_xor(acc2.y, m, 64);
        acc3.x += __shfl_xor(acc3.x, m, 64); acc3.y += __shfl_xor(acc3.y, m, 64);
    }
    if (lane < 8) {
        vfloat4* orow = (vfloat4*)(out + (size_t)wave * DIM);
        vfloat4 p0 = {acc0.x, acc0.y, acc1.x, acc1.y};
        vfloat4 p1 = {acc2.x, acc2.y, acc3.x, acc3.y};
        orow[l8 * 2] = p0; orow[l8 * 2 + 1] = p1;
    }
}

// ---------- Fallback: fully direct ----------
__global__ void direct_kernel(const int* __restrict__ x,
                              const int* __restrict__ offsets,
                              const float* __restrict__ hw,
                              const int* __restrict__ widx,
                              float* __restrict__ out,
                              int num_bags, int total_tokens, long long emb_total) {
    int wave = (int)((blockIdx.x * blockDim.x + threadIdx.x) >> 6);
    int lane = threadIdx.x & 63;
    if (wave >= num_bags) return;
    int start = offsets[wave];
    int end = (wave + 1 < num_bags) ? offsets[wave + 1] : total_tokens;
    float acc = 0.0f;
    for (int t = start; t < end; ++t) {
        int e = x[t];
        const int* row = widx + (size_t)e * DIM;
        acc += hw[row[lane]] + hw[row[emb_total + lane]];
    }
    out[(size_t)wave * DIM + lane] = acc;
}

extern "C" void kernel_launch(void* const* d_in, const int* in_sizes, int n_in,
                              void* d_out, int out_size, void* d_ws, size_t ws_size,
                              hipStream_t stream) {
    const int*   x       = (const int*)d_in[0];
    const int*   offsets = (const int*)d_in[1];
    const float* hw      = (const float*)d_in[2];
    const int*   widx    = (const int*)d_in[3];
    float*       out     = (float*)d_out;

    int total_tokens = in_sizes[0];
    int num_bags     = in_sizes[1];
    int hashed_size  = in_sizes[2];
    long long widx_elems = in_sizes[3];
    long long emb_total  = widx_elems / 2;        // NUM_EMB * DIM
    int num_emb = (int)(emb_total / DIM);

    // ws layout
    size_t esum_bytes   = (size_t)emb_total * sizeof(__half);
    size_t counts_off   = (esum_bytes + 255) & ~(size_t)255;
    size_t counts_bytes = (size_t)num_emb * sizeof(int);
    size_t bucket_off   = (counts_off + counts_bytes + 255) & ~(size_t)255;
    size_t bucket_bytes = (size_t)num_emb * BUCKET_CAP * sizeof(int);
    size_t ovfc_off     = (bucket_off + bucket_bytes + 255) & ~(size_t)255;
    size_t ovf_off      = ovfc_off + 256;
    size_t need_full    = ovf_off + (size_t)OVF_CAP * sizeof(int);

    char* ws = (char*)d_ws;

    if (ws_size >= need_full) {
        __half* esum   = (__half*)ws;
        int*    counts = (int*)(ws + counts_off);
        int*    bucket = (int*)(ws + bucket_off);
        int*    ovfc   = (int*)(ws + ovfc_off);
        int*    ovf    = (int*)(ws + ovf_off);

        hipMemsetAsync(counts, 0, counts_bytes, stream);
        hipMemsetAsync(ovfc, 0, sizeof(int), stream);
        hipMemsetAsync(out, 0, (size_t)out_size * sizeof(float), stream);

        {
            long long nthreads = (emb_total + EPT - 1) / EPT;
            long long grid = (nthreads + 255) / 256;
            emb_sum_kernel<<<(int)grid, 256, 0, stream>>>(widx, hw, esum,
                                                          emb_total, hashed_size);
        }
        {
            int grid = (total_tokens + 255) / 256;
            bin_kernel<<<grid, 256, 0, stream>>>(x, offsets, counts, bucket,
                                                 ovfc, ovf, total_tokens, num_bags);
        }
        {
            int waves_per_block = 4;
            int grid = (num_emb + waves_per_block - 1) / waves_per_block;
            scatter_kernel<<<grid, 256, 0, stream>>>(esum, counts, bucket, out, num_emb);
        }
        overflow_kernel<<<16, 256, 0, stream>>>(x, offsets, esum, out, ovfc, ovf,
                                                total_tokens, num_bags);
    } else if (ws_size >= esum_bytes) {
        __half* esum = (__half*)ws;
        {
            long long nthreads = (emb_total + EPT - 1) / EPT;
            long long grid = (nthreads + 255) / 256;
            emb_sum_kernel<<<(int)grid, 256, 0, stream>>>(widx, hw, esum,
                                                          emb_total, hashed_size);
        }
        {
            int grid = (num_bags + 3) / 4;
            bag_sum_kernel<<<grid, 256, 0, stream>>>(x, offsets, esum, out,
                                                     num_bags, total_tokens);
        }
    } else {
        int grid = (num_bags + 3) / 4;
        direct_kernel<<<grid, 256, 0, stream>>>(x, offsets, hw, widx, out,
                                                num_bags, total_tokens, emb_total);
    }
}

// Round 9
// 293.988 us; speedup vs baseline: 1.8605x; 1.8605x over previous
//
#include <hip/hip_runtime.h>
#include <hip/hip_fp16.h>

#define DIM 64
#define EPT 8        // phase-1 elements/thread (EPT=16 halved occupancy: 185->306us)
#define K_FP16 2     // hw-fp16 table = 6.4MB -> 3.2MB slices fit 4MiB per-XCD L2
#define K_FP32 8     // fallback fp32 path

typedef int          vint4   __attribute__((ext_vector_type(4)));
typedef float        vfloat4 __attribute__((ext_vector_type(4)));
typedef unsigned int vuint4  __attribute__((ext_vector_type(4)));

static __device__ __forceinline__ float2 h2f2(unsigned u) {
    __half2 h = __builtin_bit_cast(__half2, u);
    return __half22float2(h);
}

// ---------- Phase 0: hw (fp32) -> hwh (fp16), streaming ----------
__global__ void cvt_kernel(const float* __restrict__ hw,
                           __half* __restrict__ hwh, int n) {
    int base = (blockIdx.x * blockDim.x + threadIdx.x) * 8;
    if (base + 8 <= n) {
        vfloat4 f0 = __builtin_nontemporal_load((const vfloat4*)(hw + base));
        vfloat4 f1 = __builtin_nontemporal_load((const vfloat4*)(hw + base + 4));
        unsigned u[4];
        __half2 h0 = __halves2half2(__float2half_rn(f0.x), __float2half_rn(f0.y));
        __half2 h1 = __halves2half2(__float2half_rn(f0.z), __float2half_rn(f0.w));
        __half2 h2 = __halves2half2(__float2half_rn(f1.x), __float2half_rn(f1.y));
        __half2 h3 = __halves2half2(__float2half_rn(f1.z), __float2half_rn(f1.w));
        u[0] = __builtin_bit_cast(unsigned, h0);
        u[1] = __builtin_bit_cast(unsigned, h1);
        u[2] = __builtin_bit_cast(unsigned, h2);
        u[3] = __builtin_bit_cast(unsigned, h3);
        vuint4 o = {u[0], u[1], u[2], u[3]};
        *(vuint4*)(hwh + base) = o;
    } else {
        for (int i = base; i < n; ++i) hwh[i] = __float2half_rn(hw[i]);
    }
}

// ---------- Phase 1: esum[g] = (half)(hwh[widx[0][g]] + hwh[widx[1][g]]) ----------
// Cache-blocked gather from the 6.4MB fp16 table in K_FP16=2 slices.
__global__ void emb_sum_kernel(const int* __restrict__ widx,
                               const __half* __restrict__ hwh,
                               __half* __restrict__ esum,
                               long long total, int hashed_size) {
    long long base = ((long long)blockIdx.x * blockDim.x + threadIdx.x) * EPT;
    if (base >= total) return;
    if (base + EPT <= total) {
        const vint4* w0 = (const vint4*)(widx + base);
        const vint4* w1 = (const vint4*)(widx + base + total);
        vint4 a0 = __builtin_nontemporal_load(w0);
        vint4 a1 = __builtin_nontemporal_load(w0 + 1);
        vint4 b0 = __builtin_nontemporal_load(w1);
        vint4 b1 = __builtin_nontemporal_load(w1 + 1);
        int idx[16] = {a0.x, a0.y, a0.z, a0.w, a1.x, a1.y, a1.z, a1.w,
                       b0.x, b0.y, b0.z, b0.w, b1.x, b1.y, b1.z, b1.w};
        float r[16];
#pragma unroll
        for (int i = 0; i < 16; ++i) r[i] = 0.0f;
        int slice = (hashed_size + K_FP16 - 1) / K_FP16;
        int lo = 0;
#pragma unroll
        for (int k = 0; k < K_FP16; ++k, lo += slice) {
#pragma unroll
            for (int i = 0; i < 16; ++i) {
                if ((unsigned)(idx[i] - lo) < (unsigned)slice)
                    r[i] += __half2float(hwh[idx[i]]);
            }
        }
        unsigned u[4];
#pragma unroll
        for (int p = 0; p < 4; ++p) {
            float s0 = r[2 * p] + r[8 + 2 * p];
            float s1 = r[2 * p + 1] + r[8 + 2 * p + 1];
            __half2 h = __halves2half2(__float2half_rn(s0), __float2half_rn(s1));
            u[p] = __builtin_bit_cast(unsigned, h);
        }
        vuint4 o0 = {u[0], u[1], u[2], u[3]};
        __builtin_nontemporal_store(o0, (vuint4*)(esum + base));
    } else {
        for (long long g = base; g < total; ++g)
            esum[g] = __float2half_rn(__half2float(hwh[widx[g]]) +
                                      __half2float(hwh[widx[g + total]]));
    }
}

// ---------- fp32 fallback phase 1 (if ws lacks room for hwh) ----------
__global__ void emb_sum_f32_kernel(const int* __restrict__ widx,
                                   const float* __restrict__ hw,
                                   __half* __restrict__ esum,
                                   long long total, int hashed_size) {
    long long base = ((long long)blockIdx.x * blockDim.x + threadIdx.x) * EPT;
    if (base >= total) return;
    if (base + EPT <= total) {
        const vint4* w0 = (const vint4*)(widx + base);
        const vint4* w1 = (const vint4*)(widx + base + total);
        vint4 a0 = __builtin_nontemporal_load(w0);
        vint4 a1 = __builtin_nontemporal_load(w0 + 1);
        vint4 b0 = __builtin_nontemporal_load(w1);
        vint4 b1 = __builtin_nontemporal_load(w1 + 1);
        int idx[16] = {a0.x, a0.y, a0.z, a0.w, a1.x, a1.y, a1.z, a1.w,
                       b0.x, b0.y, b0.z, b0.w, b1.x, b1.y, b1.z, b1.w};
        float r[16];
#pragma unroll
        for (int i = 0; i < 16; ++i) r[i] = 0.0f;
        int slice = (hashed_size + K_FP32 - 1) / K_FP32;
        int lo = 0;
        for (int k = 0; k < K_FP32; ++k, lo += slice) {
#pragma unroll
            for (int i = 0; i < 16; ++i) {
                if ((unsigned)(idx[i] - lo) < (unsigned)slice)
                    r[i] += hw[idx[i]];
            }
        }
        unsigned u[4];
#pragma unroll
        for (int p = 0; p < 4; ++p) {
            float s0 = r[2 * p] + r[8 + 2 * p];
            float s1 = r[2 * p + 1] + r[8 + 2 * p + 1];
            __half2 h = __halves2half2(__float2half_rn(s0), __float2half_rn(s1));
            u[p] = __builtin_bit_cast(unsigned, h);
        }
        vuint4 o0 = {u[0], u[1], u[2], u[3]};
        __builtin_nontemporal_store(o0, (vuint4*)(esum + base));
    } else {
        for (long long g = base; g < total; ++g)
            esum[g] = __float2half_rn(hw[widx[g]] + hw[widx[g + total]]);
    }
}

// ---------- Phase 2: one wave per bag; 8 groups x 8 lanes, fp16 rows ----------
__global__ void __launch_bounds__(256, 8)
bag_sum_kernel(const int* __restrict__ x,
               const int* __restrict__ offsets,
               const __half* __restrict__ esum,
               float* __restrict__ out,
               int num_bags, int total_tokens) {
    int wave = (int)((blockIdx.x * blockDim.x + threadIdx.x) >> 6);
    int lane = threadIdx.x & 63;
    if (wave >= num_bags) return;
    int group = lane >> 3;   // 0..7
    int l8    = lane & 7;    // 0..7
    int start = offsets[wave];
    int end = (wave + 1 < num_bags) ? offsets[wave + 1] : total_tokens;
    int n = end - start;

    float2 acc0 = {0.f,0.f}, acc1 = {0.f,0.f}, acc2 = {0.f,0.f}, acc3 = {0.f,0.f};

    if (n == 50) {
        int xv = (lane < 50) ? x[start + lane] : 0;
        int e[7];
#pragma unroll
        for (int j = 0; j < 7; ++j) {
            int src = j * 8 + group; if (src > 49) src = 49;
            e[j] = __shfl(xv, src, 64);
        }
        vuint4 v[7];
#pragma unroll
        for (int j = 0; j < 7; ++j)
            v[j] = ((const vuint4*)(esum + (size_t)e[j] * DIM))[l8];
#pragma unroll
        for (int j = 0; j < 7; ++j) {
            bool ok = (j < 6) || (group < 2);
            if (ok) {
                float2 f0 = h2f2(v[j].x), f1 = h2f2(v[j].y);
                float2 f2 = h2f2(v[j].z), f3 = h2f2(v[j].w);
                acc0.x += f0.x; acc0.y += f0.y;
                acc1.x += f1.x; acc1.y += f1.y;
                acc2.x += f2.x; acc2.y += f2.y;
                acc3.x += f3.x; acc3.y += f3.y;
            }
        }
    } else {
        for (int base = start; base < end; base += 64) {
            int nn = end - base; if (nn > 64) nn = 64;
            int xv = (lane < nn) ? x[base + lane] : 0;
            int i = 0;
#pragma unroll 2
            for (; i + 8 <= nn; i += 8) {
                int eo = __shfl(xv, i + group, 64);
                vuint4 v = ((const vuint4*)(esum + (size_t)eo * DIM))[l8];
                float2 f0 = h2f2(v.x), f1 = h2f2(v.y), f2 = h2f2(v.z), f3 = h2f2(v.w);
                acc0.x += f0.x; acc0.y += f0.y; acc1.x += f1.x; acc1.y += f1.y;
                acc2.x += f2.x; acc2.y += f2.y; acc3.x += f3.x; acc3.y += f3.y;
            }
            if (i < nn) {
                int r = nn - i;
                int src = i + group; if (src > nn - 1) src = nn - 1;
                int eo = __shfl(xv, src, 64);
                vuint4 v = ((const vuint4*)(esum + (size_t)eo * DIM))[l8];
                if (group < r) {
                    float2 f0 = h2f2(v.x), f1 = h2f2(v.y), f2 = h2f2(v.z), f3 = h2f2(v.w);
                    acc0.x += f0.x; acc0.y += f0.y; acc1.x += f1.x; acc1.y += f1.y;
                    acc2.x += f2.x; acc2.y += f2.y; acc3.x += f3.x; acc3.y += f3.y;
                }
            }
        }
    }
#pragma unroll
    for (int m = 8; m <= 32; m <<= 1) {
        acc0.x += __shfl_xor(acc0.x, m, 64); acc0.y += __shfl_xor(acc0.y, m, 64);
        acc1.x += __shfl_xor(acc1.x, m, 64); acc1.y += __shfl_xor(acc1.y, m, 64);
        acc2.x += __shfl_xor(acc2.x, m, 64); acc2.y += __shfl_xor(acc2.y, m, 64);
        acc3.x += __shfl_xor(acc3.x, m, 64); acc3.y += __shfl_xor(acc3.y, m, 64);
    }
    if (lane < 8) {
        vfloat4* orow = (vfloat4*)(out + (size_t)wave * DIM);
        vfloat4 p0 = {acc0.x, acc0.y, acc1.x, acc1.y};
        vfloat4 p1 = {acc2.x, acc2.y, acc3.x, acc3.y};
        orow[l8 * 2] = p0; orow[l8 * 2 + 1] = p1;
    }
}

// ---------- Fallback: fully direct ----------
__global__ void direct_kernel(const int* __restrict__ x,
                              const int* __restrict__ offsets,
                              const float* __restrict__ hw,
                              const int* __restrict__ widx,
                              float* __restrict__ out,
                              int num_bags, int total_tokens, long long emb_total) {
    int wave = (int)((blockIdx.x * blockDim.x + threadIdx.x) >> 6);
    int lane = threadIdx.x & 63;
    if (wave >= num_bags) return;
    int start = offsets[wave];
    int end = (wave + 1 < num_bags) ? offsets[wave + 1] : total_tokens;
    float acc = 0.0f;
    for (int t = start; t < end; ++t) {
        int e = x[t];
        const int* row = widx + (size_t)e * DIM;
        acc += hw[row[lane]] + hw[row[emb_total + lane]];
    }
    out[(size_t)wave * DIM + lane] = acc;
}

extern "C" void kernel_launch(void* const* d_in, const int* in_sizes, int n_in,
                              void* d_out, int out_size, void* d_ws, size_t ws_size,
                              hipStream_t stream) {
    const int*   x       = (const int*)d_in[0];
    const int*   offsets = (const int*)d_in[1];
    const float* hw      = (const float*)d_in[2];
    const int*   widx    = (const int*)d_in[3];
    float*       out     = (float*)d_out;

    int total_tokens = in_sizes[0];
    int num_bags     = in_sizes[1];
    int hashed_size  = in_sizes[2];
    long long widx_elems = in_sizes[3];
    long long emb_total  = widx_elems / 2;        // NUM_EMB * DIM

    size_t esum_bytes = (size_t)emb_total * sizeof(__half);
    size_t hwh_off    = (esum_bytes + 255) & ~(size_t)255;
    size_t need_full  = hwh_off + (size_t)hashed_size * sizeof(__half);
    char* ws = (char*)d_ws;

    if (ws_size >= need_full) {
        __half* esum = (__half*)ws;
        __half* hwh  = (__half*)(ws + hwh_off);
        {
            int nthreads = (hashed_size + 7) / 8;
            int grid = (nthreads + 255) / 256;
            cvt_kernel<<<grid, 256, 0, stream>>>(hw, hwh, hashed_size);
        }
        {
            long long nthreads = (emb_total + EPT - 1) / EPT;
            long long grid = (nthreads + 255) / 256;
            emb_sum_kernel<<<(int)grid, 256, 0, stream>>>(widx, hwh, esum,
                                                          emb_total, hashed_size);
        }
        {
            int grid = (num_bags + 3) / 4;
            bag_sum_kernel<<<grid, 256, 0, stream>>>(x, offsets, esum, out,
                                                     num_bags, total_tokens);
        }
    } else if (ws_size >= esum_bytes) {
        __half* esum = (__half*)ws;
        {
            long long nthreads = (emb_total + EPT - 1) / EPT;
            long long grid = (nthreads + 255) / 256;
            emb_sum_f32_kernel<<<(int)grid, 256, 0, stream>>>(widx, hw, esum,
                                                              emb_total, hashed_size);
        }
        {
            int grid = (num_bags + 3) / 4;
            bag_sum_kernel<<<grid, 256, 0, stream>>>(x, offsets, esum, out,
                                                     num_bags, total_tokens);
        }
    } else {
        int grid = (num_bags + 3) / 4;
        direct_kernel<<<grid, 256, 0, stream>>>(x, offsets, hw, widx, out,
                                                num_bags, total_tokens, emb_total);
    }
}